// Round 7
// baseline (171.620 us; speedup 1.0000x reference)
//
#include <hip/hip_runtime.h>

// 22-qubit statevector simulator, specialized:
//   psi = G2layer * P * G1layer * P * G0layer |0>
// P = ring-CNOT permutation, bit-linear (flat bit j = qubit 21-j):
//   y_j = parity(v_j..v_21) (j<=20), y_21 = parity(v_0..v_20)
// 3-sweep pipeline (state as float2 complex):
//   kA : analytic product-state fill (first P folded in) + G1 gates v0..v12 -> bufA
//   kB : G1 gates v13..v21 + in-LDS relabel v->y + G2 {y0..y3, y14..y21} -> bufB
//   kC : 512 thr / 16K-amp (128KiB) tile {y0..y13}: G2 gates y4..y13 + |amp|^2 -> out
// Round-6 deltas vs round-5 (both numerically identical):
//  * removed 4 unnecessary intra-round barriers (kA R1/R2, kB R1/R3): those rounds
//    read and write the SAME per-thread-private element set (read-map == write-map,
//    bijective), so no cross-thread hazard exists between gates and write-back.
//  * kA copy-out round: ds_read_b128 + float4 stores (16+16 instrs vs 32+32).
// ws layout: bufA (32MiB) | bufB (32MiB) | tables (~6KB). Needs ws >= 64MiB + 8KiB.

typedef float2 cplx;

__device__ __forceinline__ cplx cmul(cplx a, cplx b) {
    return make_float2(fmaf(a.x, b.x, -a.y * b.y), fmaf(a.x, b.y, a.y * b.x));
}

// table region offsets (float2 units)
#define T_COL1 0     // 22*2
#define T_G1   64    // 22*4
#define T_G2   192   // 22*4
#define T_A0   320   // 256 : product of x-bit factors j=0..6, indexed by v bits 0..7
#define T_BT   576   // 128 : factors j=7..12, indexed by (v13<<6)|v_{7..12}

// general 2x2 complex gate on register array a[32], pair bit = BIT (compile-time)
template<int BIT>
__device__ __forceinline__ void gate32(cplx* a, const cplx* __restrict__ g) {
    const cplx g00 = g[0], g01 = g[1], g10 = g[2], g11 = g[3];
#pragma unroll
    for (int p = 0; p < 16; ++p) {
        int i0 = ((p >> BIT) << (BIT + 1)) | (p & ((1 << BIT) - 1));
        int i1 = i0 | (1 << BIT);
        cplx A = a[i0], B = a[i1];
        float ax = fmaf(g00.x, A.x, fmaf(-g00.y, A.y, fmaf(g01.x, B.x, -g01.y * B.y)));
        float ay = fmaf(g00.x, A.y, fmaf( g00.y, A.x, fmaf(g01.x, B.y,  g01.y * B.x)));
        float bx = fmaf(g10.x, A.x, fmaf(-g10.y, A.y, fmaf(g11.x, B.x, -g11.y * B.y)));
        float by = fmaf(g10.x, A.y, fmaf( g10.y, A.x, fmaf(g11.x, B.y,  g11.y * B.x)));
        a[i0] = make_float2(ax, ay);
        a[i1] = make_float2(bx, by);
    }
}

// flip-aware gate: register bit BIT = element bit BIT ^ ((s>>BIT)&1).
// When flipped, reg i0 holds e1 / i1 holds e0 -> apply PGP (swap 00<->11, 01<->10).
template<int BIT>
__device__ __forceinline__ void gate32f(cplx* a, const cplx* __restrict__ g, int s) {
    const bool flip = (s >> BIT) & 1;
    cplx g00 = g[0], g01 = g[1], g10 = g[2], g11 = g[3];
    if (flip) {
        cplx t = g00; g00 = g11; g11 = t;
        t = g01; g01 = g10; g10 = t;
    }
#pragma unroll
    for (int p = 0; p < 16; ++p) {
        int i0 = ((p >> BIT) << (BIT + 1)) | (p & ((1 << BIT) - 1));
        int i1 = i0 | (1 << BIT);
        cplx A = a[i0], B = a[i1];
        float ax = fmaf(g00.x, A.x, fmaf(-g00.y, A.y, fmaf(g01.x, B.x, -g01.y * B.y)));
        float ay = fmaf(g00.x, A.y, fmaf( g00.y, A.x, fmaf(g01.x, B.y,  g01.y * B.x)));
        float bx = fmaf(g10.x, A.x, fmaf(-g10.y, A.y, fmaf(g11.x, B.x, -g11.y * B.y)));
        float by = fmaf(g10.x, A.y, fmaf( g10.y, A.x, fmaf(g11.x, B.y,  g11.y * B.x)));
        a[i0] = make_float2(ax, ay);
        a[i1] = make_float2(bx, by);
    }
}

// kB relabel u(m) without the F term (GF2-linear in m)
__device__ constexpr int relab(int m) {
    int g = m ^ (m >> 1);
    int m0 = m & 1;
    return (g & 0x07F7) | (((g >> 3) & 1) << 3)
         | ((((g >> 11) & 1) ^ m0) << 11) | ((((m >> 12) & 1) ^ m0) << 12);
}
__device__ constexpr int mjof(int j) { return (j & 15) | (((j >> 4) & 1) << 5); }

// ---------------- setup: per-qubit matrices + fill tables -------------------
__global__ __launch_bounds__(256) void k_setup(const float* __restrict__ p, cplx* __restrict__ tab) {
    int tid = threadIdx.x;
    if (tid < 22) {
        int j = tid, q = 21 - j;  // flat bit j <-> qubit axis q
        {   // layer 0: first column of G0
            float a = 0.5f * p[3 * q], b = 0.5f * p[3 * q + 1], c = 0.5f * p[3 * q + 2];
            float cb = cosf(b), sb = sinf(b);
            tab[T_COL1 + 2 * j + 0] = make_float2(cosf(a + c) * cb, -sinf(a + c) * cb); // m00
            float ex = cosf(a - c), ey = -sinf(a - c);
            tab[T_COL1 + 2 * j + 1] = make_float2(ey * sb, -ex * sb);                   // m10
        }
        for (int L = 1; L <= 2; ++L) {
            const float* pp = p + 66 * L;
            float a = 0.5f * pp[3 * q], b = 0.5f * pp[3 * q + 1], c = 0.5f * pp[3 * q + 2];
            float cb = cosf(b), sb = sinf(b);
            cplx eac  = make_float2(cosf(a + c), -sinf(a + c)); // e^{-i(a+c)}
            cplx eca  = make_float2(cosf(c - a), -sinf(c - a)); // e^{-i(c-a)}
            cplx eacp = make_float2(eac.x, -eac.y);             // e^{+i(a+c)}
            cplx ecap = make_float2(eca.x, -eca.y);             // e^{-i(a-c)}
            cplx* G = tab + (L == 1 ? T_G1 : T_G2) + 4 * j;
            G[0] = make_float2(eac.x * cb, eac.y * cb);
            G[1] = make_float2(eca.y * sb, -eca.x * sb);
            G[2] = make_float2(ecap.y * sb, -ecap.x * sb);
            G[3] = make_float2(eacp.x * cb, eacp.y * cb);
        }
    }
    __syncthreads();
    {   // A0: factors j=0..6 over v bits 0..7 (x_j = v_j ^ v_{j+1})
        int i = tid;
        cplx v = make_float2(1.f, 0.f);
        for (int jj = 0; jj <= 6; ++jj) {
            int xb = ((i >> jj) ^ (i >> (jj + 1))) & 1;
            v = cmul(v, tab[T_COL1 + 2 * jj + xb]);
        }
        tab[T_A0 + i] = v;
    }
    if (tid < 128) { // BT: factors j=7..12 over (v13<<6)|v_{7..12}
        int i = tid;
        cplx v = make_float2(1.f, 0.f);
        for (int j = 7; j <= 11; ++j) {
            int xb = ((i >> (j - 7)) ^ (i >> (j - 6))) & 1;
            v = cmul(v, tab[T_COL1 + 2 * j + xb]);
        }
        int xb12 = ((i >> 5) ^ (i >> 6)) & 1; // x_12 = v_12 ^ v_13
        v = cmul(v, tab[T_COL1 + 24 + xb12]);
        tab[T_BT + i] = v;
    }
}

// ------------- kA: analytic fill + G1 gates on v-bits 0..12 -----------------
__global__ __launch_bounds__(256) void kA(const cplx* __restrict__ tab, cplx* __restrict__ bufA) {
    __shared__ cplx tile[8192];
    const int wg = blockIdx.x;  // v_{13..21}
    const int tid = threadIdx.x;
    const cplx* col1 = tab + T_COL1;
    const cplx* G1 = tab + T_G1;
    const int v13 = wg & 1, v20 = (wg >> 7) & 1, v21 = (wg >> 8) & 1;
    cplx H = make_float2(1.f, 0.f);
#pragma unroll
    for (int j = 13; j <= 19; ++j) { // x_j = v_j ^ v_{j+1}
        int xb = ((wg >> (j - 13)) ^ (wg >> (j - 12))) & 1;
        H = cmul(H, col1[2 * j + xb]);
    }
    {   // x_20 = v0^v20^v21, x_21 = v0^v21 ; v0 = tid&1 in R0 mapping
        int l0 = tid & 1;
        cplx s2 = cmul(col1[40 + (l0 ^ v20 ^ v21)], col1[42 + (l0 ^ v21)]);
        H = cmul(cmul(H, s2), tab[T_A0 + tid]); // A0 index = l&255 = tid (const in R0)
    }
    cplx a[32];
    // R0: l = tid | (j<<8): fill + gates v8..12 (reg bits 0..4). Conflict-free.
#pragma unroll
    for (int j = 0; j < 32; ++j)
        a[j] = cmul(H, tab[T_BT + ((j << 1) | (tid >> 7) | (v13 << 6))]);
    gate32<0>(a, G1 + 4 * 8);  gate32<1>(a, G1 + 4 * 9);  gate32<2>(a, G1 + 4 * 10);
    gate32<3>(a, G1 + 4 * 11); gate32<4>(a, G1 + 4 * 12);
#pragma unroll
    for (int j = 0; j < 32; ++j) tile[tid + (j << 8)] = a[j];
    __syncthreads();
    // R1: l = (tid&7) | (j<<3) | ((tid>>3)<<8): gates v3..7. Per-thread-private
    //     element set (read-map == write-map) -> no barrier between gates and store.
    {
        const int b1 = (tid & 7) | ((tid >> 3) << 8);
#pragma unroll
        for (int j = 0; j < 32; ++j) a[j] = tile[b1 + (j << 3)];
        gate32<0>(a, G1 + 4 * 3); gate32<1>(a, G1 + 4 * 4); gate32<2>(a, G1 + 4 * 5);
        gate32<3>(a, G1 + 4 * 6); gate32<4>(a, G1 + 4 * 7);
#pragma unroll
        for (int j = 0; j < 32; ++j) tile[b1 + (j << 3)] = a[j];
    }
    __syncthreads();
    // R2: XOR assignment l = (tid<<5) | (j ^ (tid&31)): flip-aware gates v0..2.
    //     Also per-thread-private -> no inner barrier.
    {
        char* tb = (char*)tile;
        const int b2 = tid << 8;            // byte base
        const int x2 = (tid & 31) << 3;     // byte xor
#pragma unroll
        for (int j = 0; j < 32; ++j) a[j] = *(cplx*)(tb + (b2 | ((j << 3) ^ x2)));
        gate32f<0>(a, G1 + 4 * 0, tid); gate32f<1>(a, G1 + 4 * 1, tid);
        gate32f<2>(a, G1 + 4 * 2, tid);
#pragma unroll
        for (int j = 0; j < 32; ++j) *(cplx*)(tb + (b2 | ((j << 3) ^ x2))) = a[j];
    }
    __syncthreads();
    // R3: copy-out, 2 cplx per instr: ds_read_b128 + float4 store (16+16 instrs).
    {
        const char* tb = (const char*)tile;
        float4* gA = (float4*)(bufA + (wg << 13) + 2 * tid);
#pragma unroll
        for (int j = 0; j < 16; ++j)
            gA[j << 8] = *(const float4*)(tb + 16 * tid + (j << 12));
    }
}

// -- kB: G1 v13..v21 + relabel v->y + G2 {y0..y3, y14..y21}  (bufA -> bufB) --
// tile u-coords: u_0..3 = v_0..3, u_4..12 = v_13..21 ; wg = v_4..12 (9 bits)
// m-coords: m_0..3 = y_0..3, m_4 = y_13, m_5..12 = y_14..21 (linear layouts both)
__global__ __launch_bounds__(256) void kB(const cplx* __restrict__ tab,
                                          const cplx* __restrict__ bufA, cplx* __restrict__ bufB) {
    __shared__ cplx tile[8192];
    const int wg = blockIdx.x;   // v_{4..12}
    const int tid = threadIdx.x;
    const cplx* G1 = tab + T_G1;
    const cplx* G2 = tab + T_G2;
    const int F = __popc(wg) & 1;            // parity(v4..v12)
    int W = (wg >> 8) << 8;                  // bit t (t<8): parity(v_{4+t}..v_12); bit 8: v_12
#pragma unroll
    for (int t = 0; t < 8; ++t) W |= (__popc(wg >> t) & 1) << t;
    cplx a[32];
    // R0: load (128B runs) + gates v13..17 (u4..8 = reg bits 0..4). Conflict-free.
    {
        const cplx* gA = bufA + ((tid & 15) | (wg << 4) | ((tid >> 4) << 18));
#pragma unroll
        for (int j = 0; j < 32; ++j) a[j] = gA[j << 13];
    }
    gate32<0>(a, G1 + 4 * 13); gate32<1>(a, G1 + 4 * 14); gate32<2>(a, G1 + 4 * 15);
    gate32<3>(a, G1 + 4 * 16); gate32<4>(a, G1 + 4 * 17);
    {
        const int b0 = (tid & 15) | ((tid >> 4) << 9);
#pragma unroll
        for (int j = 0; j < 32; ++j) tile[b0 + (j << 4)] = a[j];
    }
    __syncthreads();
    // R1: reg = {u9..12 (gates v18..21 on bits 0..3), u4 (bit 4)};
    //     tid: t0..3 -> u0..3, t4..7 -> u5..8. Private set -> no inner barrier.
    {
        const int b1 = (tid & 15) | (((tid >> 4) & 15) << 5);
#pragma unroll
        for (int j = 0; j < 32; ++j)
            a[j] = tile[b1 + ((j & 15) << 9) + (((j >> 4) & 1) << 4)];
        gate32<0>(a, G1 + 4 * 18); gate32<1>(a, G1 + 4 * 19);
        gate32<2>(a, G1 + 4 * 20); gate32<3>(a, G1 + 4 * 21);
#pragma unroll
        for (int j = 0; j < 32; ++j)
            tile[b1 + ((j & 15) << 9) + (((j >> 4) & 1) << 4)] = a[j];
    }
    __syncthreads();
    // R2: relabel gather. m = [(j&15)^s] | (t0<<4) | (j4<<5) | ((t>>1)<<6), s=(t>>1)&15.
    //     read phys_u = relab(m)^(F<<3) = Bt ^ relab(mj)  (GF2-linear).
    //     m-bits 0..3 = reg bits 0..3 ^ s -> FLIP-AWARE gates y0..y3; y14 (bit4=m5) direct.
    //     Read-set != write-set (true permutation) -> the inner barrier IS required.
    {
        char* tb = (char*)tile;
        const int s = (tid >> 1) & 15;
        const int mt = s | ((tid & 1) << 4) | ((tid >> 1) << 6);
        const int Bt  = (relab(mt) ^ (F << 3)) << 3;   // read byte base (u-layout)
        const int Bt2 = mt << 3;                       // write byte base (m-layout)
#pragma unroll
        for (int j = 0; j < 32; ++j)
            a[j] = *(cplx*)(tb + (Bt ^ (relab(mjof(j)) << 3)));
        gate32f<0>(a, G2 + 4 * 0, s); gate32f<1>(a, G2 + 4 * 1, s);
        gate32f<2>(a, G2 + 4 * 2, s); gate32f<3>(a, G2 + 4 * 3, s);
        gate32<4>(a, G2 + 4 * 14);
        __syncthreads();  // all gathers done before overwriting tile in m-order
#pragma unroll
        for (int j = 0; j < 32; ++j)
            *(cplx*)(tb + (Bt2 ^ (mjof(j) << 3))) = a[j];
    }
    __syncthreads();
    // R3: reg = m6..10 (gates y15..19); tid: t0..3->m0..3, t4->m4, t5->m5, t6->m11, t7->m12.
    //     Private set -> no inner barrier.
    {
        const int b3 = (tid & 15) | (((tid >> 4) & 1) << 4) | (((tid >> 5) & 1) << 5)
                     | (((tid >> 6) & 1) << 11) | (((tid >> 7) & 1) << 12);
#pragma unroll
        for (int j = 0; j < 32; ++j) a[j] = tile[b3 + (j << 6)];
        gate32<0>(a, G2 + 4 * 15); gate32<1>(a, G2 + 4 * 16); gate32<2>(a, G2 + 4 * 17);
        gate32<3>(a, G2 + 4 * 18); gate32<4>(a, G2 + 4 * 19);
#pragma unroll
        for (int j = 0; j < 32; ++j) tile[b3 + (j << 6)] = a[j];
    }
    __syncthreads();
    // R4: l = tid | (j<<8): reg bits 3,4 = m11,m12 (gates y20,y21) + global write.
    //     y addr: y_0..3 = m_0..3 ; y_4..12 = W ^ (m_4 ? 0x1FF : 0) ; y_13..21 = m_4..12
    {
#pragma unroll
        for (int j = 0; j < 32; ++j) a[j] = tile[tid + (j << 8)];
        gate32<3>(a, G2 + 4 * 20); gate32<4>(a, G2 + 4 * 21);
        const int Y9 = W ^ (((tid >> 4) & 1) ? 0x1FF : 0);
        cplx* gB = bufB + ((tid & 15) | (Y9 << 4) | (((tid >> 4) & 15) << 13));
#pragma unroll
        for (int j = 0; j < 32; ++j) gB[j << 17] = a[j];
    }
}

// ------------- kC: G2 gates y4..y13 + probs ---------------------------------
// 512 threads, 16384-amp tile (128KiB dynamic LDS), tile bits l_0..13 = y_0..13,
// wg = y_14..21 (256 blocks = 1/CU). bufB/out addresses = l | (wg<<14): contiguous.
__global__ __launch_bounds__(512) void kC(const cplx* __restrict__ tab,
                                          const cplx* __restrict__ bufB, float* __restrict__ out) {
    extern __shared__ cplx tileC[];
    const int wg = blockIdx.x;
    const int tid = threadIdx.x;
    const cplx* G2 = tab + T_G2;
    const int base = wg << 14;
    cplx a[32];
    // R0: load (128B runs); l = (t&15) | (j<<4) | ((t>>4)<<9): gates y4..8. Direct bits.
    {
        const cplx* gB = bufB + base + ((tid & 15) | ((tid >> 4) << 9));
#pragma unroll
        for (int j = 0; j < 32; ++j) a[j] = gB[j << 4];
    }
    gate32<0>(a, G2 + 4 * 4); gate32<1>(a, G2 + 4 * 5); gate32<2>(a, G2 + 4 * 6);
    gate32<3>(a, G2 + 4 * 7); gate32<4>(a, G2 + 4 * 8);
    {
        const int b0 = (tid & 15) | ((tid >> 4) << 9);
#pragma unroll
        for (int j = 0; j < 32; ++j) tileC[b0 + (j << 4)] = a[j];
    }
    __syncthreads();
    // R1: l = tid | (j<<9): gates y9..13 + probs + contiguous store. Direct bits.
#pragma unroll
    for (int j = 0; j < 32; ++j) a[j] = tileC[tid + (j << 9)];
    gate32<0>(a, G2 + 4 * 9);  gate32<1>(a, G2 + 4 * 10); gate32<2>(a, G2 + 4 * 11);
    gate32<3>(a, G2 + 4 * 12); gate32<4>(a, G2 + 4 * 13);
    {
        float* gout = out + base + tid;
#pragma unroll
        for (int j = 0; j < 32; ++j)
            gout[j << 9] = fmaf(a[j].x, a[j].x, a[j].y * a[j].y);
    }
}

extern "C" void kernel_launch(void* const* d_in, const int* in_sizes, int n_in,
                              void* d_out, int out_size, void* d_ws, size_t ws_size,
                              hipStream_t stream) {
    const float* params = (const float*)d_in[0];   // (3, 66) float32
    cplx* bufA = (cplx*)d_ws;                      // 2^22 complex
    cplx* bufB = bufA + (1 << 22);                 // 2^22 complex
    cplx* tab  = bufA + (1 << 23);                 // ~704 float2 of tables
    float* out = (float*)d_out;                    // 2^22 float probs

    k_setup<<<1, 256, 0, stream>>>(params, tab);
    kA<<<512, 256, 0, stream>>>(tab, bufA);
    kB<<<512, 256, 0, stream>>>(tab, bufA, bufB);
    kC<<<256, 512, 131072, stream>>>(tab, bufB, out);
}

// Round 8
// 121.606 us; speedup vs baseline: 1.4113x; 1.4113x over previous
//
#include <hip/hip_runtime.h>

// 22-qubit statevector simulator, specialized:
//   psi = G2layer * P * G1layer * P * G0layer |0>
// P = ring-CNOT permutation, bit-linear (flat bit j = qubit 21-j):
//   y_j = parity(v_j..v_21) (j<=20), y_21 = parity(v_0..v_20)
// 3-sweep pipeline (state as float2 complex):
//   kA : analytic product-state fill (first P folded in) + G1 gates v0..v12 -> bufA
//   kB : G1 gates v13..v21 + in-LDS relabel v->y + G2 {y0..y3, y14..y21} -> bufB
//   kC : 512 thr / 16K-amp (128KiB) tile {y0..y13}: G2 gates y4..y13 + |amp|^2 -> out
// Round-7: REVERT of round-6's barrier removal (it collapsed VALUBusy 49%->16%:
// barriers delimit phases so the compiler issues LDS reads as one 32-deep burst;
// without them it interleaves read->use at full LDS latency). Keep all inner
// barriers (round-5 structure) + kA's float4 copy-out (own phase, proven).
// ws layout: bufA (32MiB) | bufB (32MiB) | tables (~6KB). Needs ws >= 64MiB + 8KiB.

typedef float2 cplx;

__device__ __forceinline__ cplx cmul(cplx a, cplx b) {
    return make_float2(fmaf(a.x, b.x, -a.y * b.y), fmaf(a.x, b.y, a.y * b.x));
}

// table region offsets (float2 units)
#define T_COL1 0     // 22*2
#define T_G1   64    // 22*4
#define T_G2   192   // 22*4
#define T_A0   320   // 256 : product of x-bit factors j=0..6, indexed by v bits 0..7
#define T_BT   576   // 128 : factors j=7..12, indexed by (v13<<6)|v_{7..12}

// general 2x2 complex gate on register array a[32], pair bit = BIT (compile-time)
template<int BIT>
__device__ __forceinline__ void gate32(cplx* a, const cplx* __restrict__ g) {
    const cplx g00 = g[0], g01 = g[1], g10 = g[2], g11 = g[3];
#pragma unroll
    for (int p = 0; p < 16; ++p) {
        int i0 = ((p >> BIT) << (BIT + 1)) | (p & ((1 << BIT) - 1));
        int i1 = i0 | (1 << BIT);
        cplx A = a[i0], B = a[i1];
        float ax = fmaf(g00.x, A.x, fmaf(-g00.y, A.y, fmaf(g01.x, B.x, -g01.y * B.y)));
        float ay = fmaf(g00.x, A.y, fmaf( g00.y, A.x, fmaf(g01.x, B.y,  g01.y * B.x)));
        float bx = fmaf(g10.x, A.x, fmaf(-g10.y, A.y, fmaf(g11.x, B.x, -g11.y * B.y)));
        float by = fmaf(g10.x, A.y, fmaf( g10.y, A.x, fmaf(g11.x, B.y,  g11.y * B.x)));
        a[i0] = make_float2(ax, ay);
        a[i1] = make_float2(bx, by);
    }
}

// flip-aware gate: register bit BIT = element bit BIT ^ ((s>>BIT)&1).
// When flipped, reg i0 holds e1 / i1 holds e0 -> apply PGP (swap 00<->11, 01<->10).
template<int BIT>
__device__ __forceinline__ void gate32f(cplx* a, const cplx* __restrict__ g, int s) {
    const bool flip = (s >> BIT) & 1;
    cplx g00 = g[0], g01 = g[1], g10 = g[2], g11 = g[3];
    if (flip) {
        cplx t = g00; g00 = g11; g11 = t;
        t = g01; g01 = g10; g10 = t;
    }
#pragma unroll
    for (int p = 0; p < 16; ++p) {
        int i0 = ((p >> BIT) << (BIT + 1)) | (p & ((1 << BIT) - 1));
        int i1 = i0 | (1 << BIT);
        cplx A = a[i0], B = a[i1];
        float ax = fmaf(g00.x, A.x, fmaf(-g00.y, A.y, fmaf(g01.x, B.x, -g01.y * B.y)));
        float ay = fmaf(g00.x, A.y, fmaf( g00.y, A.x, fmaf(g01.x, B.y,  g01.y * B.x)));
        float bx = fmaf(g10.x, A.x, fmaf(-g10.y, A.y, fmaf(g11.x, B.x, -g11.y * B.y)));
        float by = fmaf(g10.x, A.y, fmaf( g10.y, A.x, fmaf(g11.x, B.y,  g11.y * B.x)));
        a[i0] = make_float2(ax, ay);
        a[i1] = make_float2(bx, by);
    }
}

// kB relabel u(m) without the F term (GF2-linear in m)
__device__ constexpr int relab(int m) {
    int g = m ^ (m >> 1);
    int m0 = m & 1;
    return (g & 0x07F7) | (((g >> 3) & 1) << 3)
         | ((((g >> 11) & 1) ^ m0) << 11) | ((((m >> 12) & 1) ^ m0) << 12);
}
__device__ constexpr int mjof(int j) { return (j & 15) | (((j >> 4) & 1) << 5); }

// ---------------- setup: per-qubit matrices + fill tables -------------------
__global__ __launch_bounds__(256) void k_setup(const float* __restrict__ p, cplx* __restrict__ tab) {
    int tid = threadIdx.x;
    if (tid < 22) {
        int j = tid, q = 21 - j;  // flat bit j <-> qubit axis q
        {   // layer 0: first column of G0
            float a = 0.5f * p[3 * q], b = 0.5f * p[3 * q + 1], c = 0.5f * p[3 * q + 2];
            float cb = cosf(b), sb = sinf(b);
            tab[T_COL1 + 2 * j + 0] = make_float2(cosf(a + c) * cb, -sinf(a + c) * cb); // m00
            float ex = cosf(a - c), ey = -sinf(a - c);
            tab[T_COL1 + 2 * j + 1] = make_float2(ey * sb, -ex * sb);                   // m10
        }
        for (int L = 1; L <= 2; ++L) {
            const float* pp = p + 66 * L;
            float a = 0.5f * pp[3 * q], b = 0.5f * pp[3 * q + 1], c = 0.5f * pp[3 * q + 2];
            float cb = cosf(b), sb = sinf(b);
            cplx eac  = make_float2(cosf(a + c), -sinf(a + c)); // e^{-i(a+c)}
            cplx eca  = make_float2(cosf(c - a), -sinf(c - a)); // e^{-i(c-a)}
            cplx eacp = make_float2(eac.x, -eac.y);             // e^{+i(a+c)}
            cplx ecap = make_float2(eca.x, -eca.y);             // e^{-i(a-c)}
            cplx* G = tab + (L == 1 ? T_G1 : T_G2) + 4 * j;
            G[0] = make_float2(eac.x * cb, eac.y * cb);
            G[1] = make_float2(eca.y * sb, -eca.x * sb);
            G[2] = make_float2(ecap.y * sb, -ecap.x * sb);
            G[3] = make_float2(eacp.x * cb, eacp.y * cb);
        }
    }
    __syncthreads();
    {   // A0: factors j=0..6 over v bits 0..7 (x_j = v_j ^ v_{j+1})
        int i = tid;
        cplx v = make_float2(1.f, 0.f);
        for (int jj = 0; jj <= 6; ++jj) {
            int xb = ((i >> jj) ^ (i >> (jj + 1))) & 1;
            v = cmul(v, tab[T_COL1 + 2 * jj + xb]);
        }
        tab[T_A0 + i] = v;
    }
    if (tid < 128) { // BT: factors j=7..12 over (v13<<6)|v_{7..12}
        int i = tid;
        cplx v = make_float2(1.f, 0.f);
        for (int j = 7; j <= 11; ++j) {
            int xb = ((i >> (j - 7)) ^ (i >> (j - 6))) & 1;
            v = cmul(v, tab[T_COL1 + 2 * j + xb]);
        }
        int xb12 = ((i >> 5) ^ (i >> 6)) & 1; // x_12 = v_12 ^ v_13
        v = cmul(v, tab[T_COL1 + 24 + xb12]);
        tab[T_BT + i] = v;
    }
}

// ------------- kA: analytic fill + G1 gates on v-bits 0..12 -----------------
__global__ __launch_bounds__(256) void kA(const cplx* __restrict__ tab, cplx* __restrict__ bufA) {
    __shared__ cplx tile[8192];
    const int wg = blockIdx.x;  // v_{13..21}
    const int tid = threadIdx.x;
    const cplx* col1 = tab + T_COL1;
    const cplx* G1 = tab + T_G1;
    const int v13 = wg & 1, v20 = (wg >> 7) & 1, v21 = (wg >> 8) & 1;
    cplx H = make_float2(1.f, 0.f);
#pragma unroll
    for (int j = 13; j <= 19; ++j) { // x_j = v_j ^ v_{j+1}
        int xb = ((wg >> (j - 13)) ^ (wg >> (j - 12))) & 1;
        H = cmul(H, col1[2 * j + xb]);
    }
    {   // x_20 = v0^v20^v21, x_21 = v0^v21 ; v0 = tid&1 in R0 mapping
        int l0 = tid & 1;
        cplx s2 = cmul(col1[40 + (l0 ^ v20 ^ v21)], col1[42 + (l0 ^ v21)]);
        H = cmul(cmul(H, s2), tab[T_A0 + tid]); // A0 index = l&255 = tid (const in R0)
    }
    cplx a[32];
    // R0: l = tid | (j<<8): fill + gates v8..12 (reg bits 0..4). Conflict-free.
#pragma unroll
    for (int j = 0; j < 32; ++j)
        a[j] = cmul(H, tab[T_BT + ((j << 1) | (tid >> 7) | (v13 << 6))]);
    gate32<0>(a, G1 + 4 * 8);  gate32<1>(a, G1 + 4 * 9);  gate32<2>(a, G1 + 4 * 10);
    gate32<3>(a, G1 + 4 * 11); gate32<4>(a, G1 + 4 * 12);
#pragma unroll
    for (int j = 0; j < 32; ++j) tile[tid + (j << 8)] = a[j];
    __syncthreads();
    // R1: l = (tid&7) | (j<<3) | ((tid>>3)<<8): gates v3..7 (reg bits 0..4, direct).
    //     Inner barrier kept: it delimits the LDS read-burst / VALU / write-burst
    //     phases for the scheduler (round-6 removal collapsed VALUBusy 49%->16%).
    {
        const int b1 = (tid & 7) | ((tid >> 3) << 8);
#pragma unroll
        for (int j = 0; j < 32; ++j) a[j] = tile[b1 + (j << 3)];
        gate32<0>(a, G1 + 4 * 3); gate32<1>(a, G1 + 4 * 4); gate32<2>(a, G1 + 4 * 5);
        gate32<3>(a, G1 + 4 * 6); gate32<4>(a, G1 + 4 * 7);
        __syncthreads();
#pragma unroll
        for (int j = 0; j < 32; ++j) tile[b1 + (j << 3)] = a[j];
    }
    __syncthreads();
    // R2: XOR assignment l = (tid<<5) | (j ^ (tid&31)): flip-aware gates v0..2.
    {
        char* tb = (char*)tile;
        const int b2 = tid << 8;            // byte base
        const int x2 = (tid & 31) << 3;     // byte xor
#pragma unroll
        for (int j = 0; j < 32; ++j) a[j] = *(cplx*)(tb + (b2 | ((j << 3) ^ x2)));
        gate32f<0>(a, G1 + 4 * 0, tid); gate32f<1>(a, G1 + 4 * 1, tid);
        gate32f<2>(a, G1 + 4 * 2, tid);
        __syncthreads();
#pragma unroll
        for (int j = 0; j < 32; ++j) *(cplx*)(tb + (b2 | ((j << 3) ^ x2))) = a[j];
    }
    __syncthreads();
    // R3: copy-out, 2 cplx per instr: ds_read_b128 + float4 store (16+16 instrs).
    {
        const char* tb = (const char*)tile;
        float4* gA = (float4*)(bufA + (wg << 13) + 2 * tid);
#pragma unroll
        for (int j = 0; j < 16; ++j)
            gA[j << 8] = *(const float4*)(tb + 16 * tid + (j << 12));
    }
}

// -- kB: G1 v13..v21 + relabel v->y + G2 {y0..y3, y14..y21}  (bufA -> bufB) --
// tile u-coords: u_0..3 = v_0..3, u_4..12 = v_13..21 ; wg = v_4..12 (9 bits)
// m-coords: m_0..3 = y_0..3, m_4 = y_13, m_5..12 = y_14..21 (linear layouts both)
__global__ __launch_bounds__(256) void kB(const cplx* __restrict__ tab,
                                          const cplx* __restrict__ bufA, cplx* __restrict__ bufB) {
    __shared__ cplx tile[8192];
    const int wg = blockIdx.x;   // v_{4..12}
    const int tid = threadIdx.x;
    const cplx* G1 = tab + T_G1;
    const cplx* G2 = tab + T_G2;
    const int F = __popc(wg) & 1;            // parity(v4..v12)
    int W = (wg >> 8) << 8;                  // bit t (t<8): parity(v_{4+t}..v_12); bit 8: v_12
#pragma unroll
    for (int t = 0; t < 8; ++t) W |= (__popc(wg >> t) & 1) << t;
    cplx a[32];
    // R0: load (128B runs) + gates v13..17 (u4..8 = reg bits 0..4). Conflict-free.
    {
        const cplx* gA = bufA + ((tid & 15) | (wg << 4) | ((tid >> 4) << 18));
#pragma unroll
        for (int j = 0; j < 32; ++j) a[j] = gA[j << 13];
    }
    gate32<0>(a, G1 + 4 * 13); gate32<1>(a, G1 + 4 * 14); gate32<2>(a, G1 + 4 * 15);
    gate32<3>(a, G1 + 4 * 16); gate32<4>(a, G1 + 4 * 17);
    {
        const int b0 = (tid & 15) | ((tid >> 4) << 9);
#pragma unroll
        for (int j = 0; j < 32; ++j) tile[b0 + (j << 4)] = a[j];
    }
    __syncthreads();
    // R1: reg = {u9..12 (gates v18..21 on bits 0..3), u4 (bit 4)};
    //     tid: t0..3 -> u0..3, t4..7 -> u5..8. Inner barrier kept (phase structure).
    {
        const int b1 = (tid & 15) | (((tid >> 4) & 15) << 5);
#pragma unroll
        for (int j = 0; j < 32; ++j)
            a[j] = tile[b1 + ((j & 15) << 9) + (((j >> 4) & 1) << 4)];
        gate32<0>(a, G1 + 4 * 18); gate32<1>(a, G1 + 4 * 19);
        gate32<2>(a, G1 + 4 * 20); gate32<3>(a, G1 + 4 * 21);
        __syncthreads();
#pragma unroll
        for (int j = 0; j < 32; ++j)
            tile[b1 + ((j & 15) << 9) + (((j >> 4) & 1) << 4)] = a[j];
    }
    __syncthreads();
    // R2: relabel gather. m = [(j&15)^s] | (t0<<4) | (j4<<5) | ((t>>1)<<6), s=(t>>1)&15.
    //     read phys_u = relab(m)^(F<<3) = Bt ^ relab(mj)  (GF2-linear).
    //     m-bits 0..3 = reg bits 0..3 ^ s -> FLIP-AWARE gates y0..y3; y14 (bit4=m5) direct.
    {
        char* tb = (char*)tile;
        const int s = (tid >> 1) & 15;
        const int mt = s | ((tid & 1) << 4) | ((tid >> 1) << 6);
        const int Bt  = (relab(mt) ^ (F << 3)) << 3;   // read byte base (u-layout)
        const int Bt2 = mt << 3;                       // write byte base (m-layout)
#pragma unroll
        for (int j = 0; j < 32; ++j)
            a[j] = *(cplx*)(tb + (Bt ^ (relab(mjof(j)) << 3)));
        gate32f<0>(a, G2 + 4 * 0, s); gate32f<1>(a, G2 + 4 * 1, s);
        gate32f<2>(a, G2 + 4 * 2, s); gate32f<3>(a, G2 + 4 * 3, s);
        gate32<4>(a, G2 + 4 * 14);
        __syncthreads();  // all gathers done before overwriting tile in m-order
#pragma unroll
        for (int j = 0; j < 32; ++j)
            *(cplx*)(tb + (Bt2 ^ (mjof(j) << 3))) = a[j];
    }
    __syncthreads();
    // R3: reg = m6..10 (gates y15..19); tid: t0..3->m0..3, t4->m4, t5->m5, t6->m11, t7->m12.
    //     Inner barrier kept (phase structure).
    {
        const int b3 = (tid & 15) | (((tid >> 4) & 1) << 4) | (((tid >> 5) & 1) << 5)
                     | (((tid >> 6) & 1) << 11) | (((tid >> 7) & 1) << 12);
#pragma unroll
        for (int j = 0; j < 32; ++j) a[j] = tile[b3 + (j << 6)];
        gate32<0>(a, G2 + 4 * 15); gate32<1>(a, G2 + 4 * 16); gate32<2>(a, G2 + 4 * 17);
        gate32<3>(a, G2 + 4 * 18); gate32<4>(a, G2 + 4 * 19);
        __syncthreads();
#pragma unroll
        for (int j = 0; j < 32; ++j) tile[b3 + (j << 6)] = a[j];
    }
    __syncthreads();
    // R4: l = tid | (j<<8): reg bits 3,4 = m11,m12 (gates y20,y21) + global write.
    //     y addr: y_0..3 = m_0..3 ; y_4..12 = W ^ (m_4 ? 0x1FF : 0) ; y_13..21 = m_4..12
    {
#pragma unroll
        for (int j = 0; j < 32; ++j) a[j] = tile[tid + (j << 8)];
        gate32<3>(a, G2 + 4 * 20); gate32<4>(a, G2 + 4 * 21);
        const int Y9 = W ^ (((tid >> 4) & 1) ? 0x1FF : 0);
        cplx* gB = bufB + ((tid & 15) | (Y9 << 4) | (((tid >> 4) & 15) << 13));
#pragma unroll
        for (int j = 0; j < 32; ++j) gB[j << 17] = a[j];
    }
}

// ------------- kC: G2 gates y4..y13 + probs ---------------------------------
// 512 threads, 16384-amp tile (128KiB dynamic LDS), tile bits l_0..13 = y_0..13,
// wg = y_14..21 (256 blocks = 1/CU). bufB/out addresses = l | (wg<<14): contiguous.
__global__ __launch_bounds__(512) void kC(const cplx* __restrict__ tab,
                                          const cplx* __restrict__ bufB, float* __restrict__ out) {
    extern __shared__ cplx tileC[];
    const int wg = blockIdx.x;
    const int tid = threadIdx.x;
    const cplx* G2 = tab + T_G2;
    const int base = wg << 14;
    cplx a[32];
    // R0: load (128B runs); l = (t&15) | (j<<4) | ((t>>4)<<9): gates y4..8. Direct bits.
    {
        const cplx* gB = bufB + base + ((tid & 15) | ((tid >> 4) << 9));
#pragma unroll
        for (int j = 0; j < 32; ++j) a[j] = gB[j << 4];
    }
    gate32<0>(a, G2 + 4 * 4); gate32<1>(a, G2 + 4 * 5); gate32<2>(a, G2 + 4 * 6);
    gate32<3>(a, G2 + 4 * 7); gate32<4>(a, G2 + 4 * 8);
    {
        const int b0 = (tid & 15) | ((tid >> 4) << 9);
#pragma unroll
        for (int j = 0; j < 32; ++j) tileC[b0 + (j << 4)] = a[j];
    }
    __syncthreads();
    // R1: l = tid | (j<<9): gates y9..13 + probs + contiguous store. Direct bits.
#pragma unroll
    for (int j = 0; j < 32; ++j) a[j] = tileC[tid + (j << 9)];
    gate32<0>(a, G2 + 4 * 9);  gate32<1>(a, G2 + 4 * 10); gate32<2>(a, G2 + 4 * 11);
    gate32<3>(a, G2 + 4 * 12); gate32<4>(a, G2 + 4 * 13);
    {
        float* gout = out + base + tid;
#pragma unroll
        for (int j = 0; j < 32; ++j)
            gout[j << 9] = fmaf(a[j].x, a[j].x, a[j].y * a[j].y);
    }
}

extern "C" void kernel_launch(void* const* d_in, const int* in_sizes, int n_in,
                              void* d_out, int out_size, void* d_ws, size_t ws_size,
                              hipStream_t stream) {
    const float* params = (const float*)d_in[0];   // (3, 66) float32
    cplx* bufA = (cplx*)d_ws;                      // 2^22 complex
    cplx* bufB = bufA + (1 << 22);                 // 2^22 complex
    cplx* tab  = bufA + (1 << 23);                 // ~704 float2 of tables
    float* out = (float*)d_out;                    // 2^22 float probs

    k_setup<<<1, 256, 0, stream>>>(params, tab);
    kA<<<512, 256, 0, stream>>>(tab, bufA);
    kB<<<512, 256, 0, stream>>>(tab, bufA, bufB);
    kC<<<256, 512, 131072, stream>>>(tab, bufB, out);
}

// Round 9
// 115.415 us; speedup vs baseline: 1.4870x; 1.0536x over previous
//
#include <hip/hip_runtime.h>

// 22-qubit statevector simulator, specialized:
//   psi = G2layer * P * G1layer * P * G0layer |0>
// P = ring-CNOT permutation, bit-linear (flat bit j = qubit 21-j):
//   y_j = parity(v_j..v_21) (j<=20), y_21 = parity(v_0..v_20)
// 3-sweep pipeline (state as float2 complex):
//   kA : 512thr/16reg/64KiB tile {v0..12}: fill + G1 v0..v12 -> bufA
//   kB : 512thr/16reg/64KiB tile {v0..3,v13..21}: G1 v13..21 + relabel + G2 {y0..3,y14..21}
//   kC : 1024thr/16reg/128KiB tile {y0..13}: G2 y4..y13 + |amp|^2 -> out
// Round-8: occupancy push. Same tile shapes/maps as the passing round-7 kernel,
// but 2x threads with 16 regs/thread -> 4 waves/SIMD (was 2). Rounds apply 4
// gates each (16 regs = 4 pair bits). Phase barriers kept (round-6 lesson).
// ws layout: bufA (32MiB) | bufB (32MiB) | tables (~6KB). Needs ws >= 64MiB + 8KiB.

typedef float2 cplx;

__device__ __forceinline__ cplx cmul(cplx a, cplx b) {
    return make_float2(fmaf(a.x, b.x, -a.y * b.y), fmaf(a.x, b.y, a.y * b.x));
}

// table region offsets (float2 units)
#define T_COL1 0     // 22*2
#define T_G1   64    // 22*4
#define T_G2   192   // 22*4
#define T_A0   320   // 256 : product of x-bit factors j=0..6, indexed by v bits 0..7
#define T_BT   576   // 128 : factors j=7..12, indexed by (v13<<6)|v_{7..12}

// 2x2 complex gate on register array a[N], pair bit = BIT (compile-time)
template<int BIT, int N>
__device__ __forceinline__ void gateN(cplx* a, const cplx* __restrict__ g) {
    const cplx g00 = g[0], g01 = g[1], g10 = g[2], g11 = g[3];
#pragma unroll
    for (int p = 0; p < N / 2; ++p) {
        int i0 = ((p >> BIT) << (BIT + 1)) | (p & ((1 << BIT) - 1));
        int i1 = i0 | (1 << BIT);
        cplx A = a[i0], B = a[i1];
        float ax = fmaf(g00.x, A.x, fmaf(-g00.y, A.y, fmaf(g01.x, B.x, -g01.y * B.y)));
        float ay = fmaf(g00.x, A.y, fmaf( g00.y, A.x, fmaf(g01.x, B.y,  g01.y * B.x)));
        float bx = fmaf(g10.x, A.x, fmaf(-g10.y, A.y, fmaf(g11.x, B.x, -g11.y * B.y)));
        float by = fmaf(g10.x, A.y, fmaf( g10.y, A.x, fmaf(g11.x, B.y,  g11.y * B.x)));
        a[i0] = make_float2(ax, ay);
        a[i1] = make_float2(bx, by);
    }
}

// flip-aware gate: register bit BIT = element bit BIT ^ ((s>>BIT)&1).
// When flipped, reg i0 holds e1 / i1 holds e0 -> apply PGP (swap 00<->11, 01<->10).
template<int BIT, int N>
__device__ __forceinline__ void gateNf(cplx* a, const cplx* __restrict__ g, int s) {
    const bool flip = (s >> BIT) & 1;
    cplx g00 = g[0], g01 = g[1], g10 = g[2], g11 = g[3];
    if (flip) {
        cplx t = g00; g00 = g11; g11 = t;
        t = g01; g01 = g10; g10 = t;
    }
#pragma unroll
    for (int p = 0; p < N / 2; ++p) {
        int i0 = ((p >> BIT) << (BIT + 1)) | (p & ((1 << BIT) - 1));
        int i1 = i0 | (1 << BIT);
        cplx A = a[i0], B = a[i1];
        float ax = fmaf(g00.x, A.x, fmaf(-g00.y, A.y, fmaf(g01.x, B.x, -g01.y * B.y)));
        float ay = fmaf(g00.x, A.y, fmaf( g00.y, A.x, fmaf(g01.x, B.y,  g01.y * B.x)));
        float bx = fmaf(g10.x, A.x, fmaf(-g10.y, A.y, fmaf(g11.x, B.x, -g11.y * B.y)));
        float by = fmaf(g10.x, A.y, fmaf( g10.y, A.x, fmaf(g11.x, B.y,  g11.y * B.x)));
        a[i0] = make_float2(ax, ay);
        a[i1] = make_float2(bx, by);
    }
}

// kB relabel u(m) without the F term (GF2-linear in m)
__device__ constexpr int relab(int m) {
    int g = m ^ (m >> 1);
    int m0 = m & 1;
    return (g & 0x07F7) | (((g >> 3) & 1) << 3)
         | ((((g >> 11) & 1) ^ m0) << 11) | ((((m >> 12) & 1) ^ m0) << 12);
}
// relab restricted to 4-bit inputs (== relab(x) for x<16); GF2-linear.
__device__ constexpr int relab4(int x) {
    return (x ^ (x >> 1)) | ((x & 1) ? 0x1800 : 0);
}

// ---------------- setup: per-qubit matrices + fill tables -------------------
__global__ __launch_bounds__(256) void k_setup(const float* __restrict__ p, cplx* __restrict__ tab) {
    int tid = threadIdx.x;
    if (tid < 22) {
        int j = tid, q = 21 - j;  // flat bit j <-> qubit axis q
        {   // layer 0: first column of G0
            float a = 0.5f * p[3 * q], b = 0.5f * p[3 * q + 1], c = 0.5f * p[3 * q + 2];
            float cb = cosf(b), sb = sinf(b);
            tab[T_COL1 + 2 * j + 0] = make_float2(cosf(a + c) * cb, -sinf(a + c) * cb); // m00
            float ex = cosf(a - c), ey = -sinf(a - c);
            tab[T_COL1 + 2 * j + 1] = make_float2(ey * sb, -ex * sb);                   // m10
        }
        for (int L = 1; L <= 2; ++L) {
            const float* pp = p + 66 * L;
            float a = 0.5f * pp[3 * q], b = 0.5f * pp[3 * q + 1], c = 0.5f * pp[3 * q + 2];
            float cb = cosf(b), sb = sinf(b);
            cplx eac  = make_float2(cosf(a + c), -sinf(a + c)); // e^{-i(a+c)}
            cplx eca  = make_float2(cosf(c - a), -sinf(c - a)); // e^{-i(c-a)}
            cplx eacp = make_float2(eac.x, -eac.y);             // e^{+i(a+c)}
            cplx ecap = make_float2(eca.x, -eca.y);             // e^{-i(a-c)}
            cplx* G = tab + (L == 1 ? T_G1 : T_G2) + 4 * j;
            G[0] = make_float2(eac.x * cb, eac.y * cb);
            G[1] = make_float2(eca.y * sb, -eca.x * sb);
            G[2] = make_float2(ecap.y * sb, -ecap.x * sb);
            G[3] = make_float2(eacp.x * cb, eacp.y * cb);
        }
    }
    __syncthreads();
    {   // A0: factors j=0..6 over v bits 0..7 (x_j = v_j ^ v_{j+1})
        int i = tid;
        cplx v = make_float2(1.f, 0.f);
        for (int jj = 0; jj <= 6; ++jj) {
            int xb = ((i >> jj) ^ (i >> (jj + 1))) & 1;
            v = cmul(v, tab[T_COL1 + 2 * jj + xb]);
        }
        tab[T_A0 + i] = v;
    }
    if (tid < 128) { // BT: factors j=7..12 over (v13<<6)|v_{7..12}
        int i = tid;
        cplx v = make_float2(1.f, 0.f);
        for (int j = 7; j <= 11; ++j) {
            int xb = ((i >> (j - 7)) ^ (i >> (j - 6))) & 1;
            v = cmul(v, tab[T_COL1 + 2 * j + xb]);
        }
        int xb12 = ((i >> 5) ^ (i >> 6)) & 1; // x_12 = v_12 ^ v_13
        v = cmul(v, tab[T_COL1 + 24 + xb12]);
        tab[T_BT + i] = v;
    }
}

// ------------- kA: analytic fill + G1 gates on v-bits 0..12 -----------------
// 512 thr, tile 8192 = bits v0..12; tid = 9 bits, 16 regs = 4 bits per round.
__global__ __launch_bounds__(512, 4) void kA(const cplx* __restrict__ tab, cplx* __restrict__ bufA) {
    __shared__ cplx tile[8192];
    const int wg = blockIdx.x;  // v_{13..21}
    const int tid = threadIdx.x;
    const cplx* col1 = tab + T_COL1;
    const cplx* G1 = tab + T_G1;
    const int v13 = wg & 1, v20 = (wg >> 7) & 1, v21 = (wg >> 8) & 1;
    cplx H = make_float2(1.f, 0.f);
#pragma unroll
    for (int j = 13; j <= 19; ++j) { // x_j = v_j ^ v_{j+1}
        int xb = ((wg >> (j - 13)) ^ (wg >> (j - 12))) & 1;
        H = cmul(H, col1[2 * j + xb]);
    }
    {   // x_20 = v0^v20^v21, x_21 = v0^v21 ; v0 = tid&1 (R0 mapping)
        int l0 = tid & 1;
        cplx s2 = cmul(col1[40 + (l0 ^ v20 ^ v21)], col1[42 + (l0 ^ v21)]);
        H = cmul(cmul(H, s2), tab[T_A0 + (tid & 255)]); // A0 over v0..7 = tid low 8
    }
    cplx a[16];
    // R0: l = tid | (j<<9): fill (BT over v7..12,v13) + gates v9..12 (reg bits 0..3)
#pragma unroll
    for (int j = 0; j < 16; ++j)
        a[j] = cmul(H, tab[T_BT + (((tid >> 7) & 3) | (j << 2) | (v13 << 6))]);
    gateN<0,16>(a, G1 + 4 * 9);  gateN<1,16>(a, G1 + 4 * 10);
    gateN<2,16>(a, G1 + 4 * 11); gateN<3,16>(a, G1 + 4 * 12);
#pragma unroll
    for (int j = 0; j < 16; ++j) tile[tid + (j << 9)] = a[j];
    __syncthreads();
    // R1: l = (tid&31) | (j<<5) | ((tid>>5)<<9): gates v5..8
    {
        const int b1 = (tid & 31) | ((tid >> 5) << 9);
#pragma unroll
        for (int j = 0; j < 16; ++j) a[j] = tile[b1 + (j << 5)];
        gateN<0,16>(a, G1 + 4 * 5); gateN<1,16>(a, G1 + 4 * 6);
        gateN<2,16>(a, G1 + 4 * 7); gateN<3,16>(a, G1 + 4 * 8);
        __syncthreads();
#pragma unroll
        for (int j = 0; j < 16; ++j) tile[b1 + (j << 5)] = a[j];
    }
    __syncthreads();
    // R2: l = (tid&1) | (((j^s)&15)<<1) | ((tid>>1)<<5): flip-aware gates v1..4
    {
        const int s = (tid >> 1) & 15;
        const int b2 = (tid & 1) | ((tid >> 1) << 5);
#pragma unroll
        for (int j = 0; j < 16; ++j) a[j] = tile[b2 + (((j ^ s) & 15) << 1)];
        gateNf<0,16>(a, G1 + 4 * 1, s); gateNf<1,16>(a, G1 + 4 * 2, s);
        gateNf<2,16>(a, G1 + 4 * 3, s); gateNf<3,16>(a, G1 + 4 * 4, s);
        __syncthreads();
#pragma unroll
        for (int j = 0; j < 16; ++j) tile[b2 + (((j ^ s) & 15) << 1)] = a[j];
    }
    __syncthreads();
    // R3: pairs (l0=0,1) via b128; gate v0; float4 store (1KB/wave contiguous)
    {
        const char* tb = (const char*)tile;
#pragma unroll
        for (int h = 0; h < 8; ++h) {
            float4 f = *(const float4*)(tb + 16 * tid + (h << 13));
            a[2 * h]     = make_float2(f.x, f.y);
            a[2 * h + 1] = make_float2(f.z, f.w);
        }
        gateN<0,16>(a, G1 + 4 * 0);
        float4* gA = (float4*)(bufA + (wg << 13));
#pragma unroll
        for (int h = 0; h < 8; ++h)
            gA[tid | (h << 9)] = make_float4(a[2*h].x, a[2*h].y, a[2*h+1].x, a[2*h+1].y);
    }
}

// -- kB: G1 v13..v21 + relabel v->y + G2 {y0..y3, y14..y21}  (bufA -> bufB) --
// 512 thr. tile u-coords: u0..3 = v0..3, u4..12 = v13..21 ; wg = v4..12 (9 bits)
// m-coords: m0..3 = y0..3, m4 = y13, m5..12 = y14..21 (linear layouts both)
__global__ __launch_bounds__(512, 4) void kB(const cplx* __restrict__ tab,
                                             const cplx* __restrict__ bufA, cplx* __restrict__ bufB) {
    __shared__ cplx tile[8192];
    const int wg = blockIdx.x;   // v_{4..12}
    const int tid = threadIdx.x;
    const cplx* G1 = tab + T_G1;
    const cplx* G2 = tab + T_G2;
    const int F = __popc(wg) & 1;            // parity(v4..v12)
    int W = (wg >> 8) << 8;                  // bit t (t<8): parity(v_{4+t}..v_12); bit 8: v_12
#pragma unroll
    for (int t = 0; t < 8; ++t) W |= (__popc(wg >> t) & 1) << t;
    cplx a[16];
    // R0: load (128B runs) + gates v13..16 (u4..7 = reg bits 0..3)
    {
        const cplx* gA = bufA + ((tid & 15) | (wg << 4) | (((tid >> 4) & 31) << 17));
#pragma unroll
        for (int j = 0; j < 16; ++j) a[j] = gA[j << 13];
        gateN<0,16>(a, G1 + 4 * 13); gateN<1,16>(a, G1 + 4 * 14);
        gateN<2,16>(a, G1 + 4 * 15); gateN<3,16>(a, G1 + 4 * 16);
        const int b0 = (tid & 15) | ((tid >> 4) << 8);
#pragma unroll
        for (int j = 0; j < 16; ++j) tile[b0 + (j << 4)] = a[j];
    }
    __syncthreads();
    // R1: l = (tid&255) | (j<<8) | ((tid>>8)<<12): gates v17..20 (u8..11)
    {
        const int b1 = (tid & 255) | ((tid >> 8) << 12);
#pragma unroll
        for (int j = 0; j < 16; ++j) a[j] = tile[b1 + (j << 8)];
        gateN<0,16>(a, G1 + 4 * 17); gateN<1,16>(a, G1 + 4 * 18);
        gateN<2,16>(a, G1 + 4 * 19); gateN<3,16>(a, G1 + 4 * 20);
        __syncthreads();
#pragma unroll
        for (int j = 0; j < 16; ++j) tile[b1 + (j << 8)] = a[j];
    }
    __syncthreads();
    // R2: l = tid | (j<<9): gate v21 (u12 = reg bit 3); bits 9..11 are fillers
    {
#pragma unroll
        for (int j = 0; j < 16; ++j) a[j] = tile[tid + (j << 9)];
        gateN<3,16>(a, G1 + 4 * 21);
        __syncthreads();
#pragma unroll
        for (int j = 0; j < 16; ++j) tile[tid + (j << 9)] = a[j];
    }
    __syncthreads();
    // R3: relabel gather. m = ((j^s)&15) | (tid<<4), s = (tid>>1)&15.
    //     read u-layout: addr = relab(m)^(F<<3) = Bte ^ relab4(j)  (GF2-linear,
    //     relab4(s) folded into Bte). Flip-aware gates y0..3; write m-layout.
    {
        const int s = (tid >> 1) & 15;
        const int Bte = relab(tid << 4) ^ (F << 3) ^ relab4(s);
        const int Bw  = (tid << 4) | s;      // write addr = Bw ^ j
#pragma unroll
        for (int j = 0; j < 16; ++j) a[j] = tile[Bte ^ relab4(j)];
        gateNf<0,16>(a, G2 + 4 * 0, s); gateNf<1,16>(a, G2 + 4 * 1, s);
        gateNf<2,16>(a, G2 + 4 * 2, s); gateNf<3,16>(a, G2 + 4 * 3, s);
        __syncthreads();  // all gathers done before overwriting tile in m-order
#pragma unroll
        for (int j = 0; j < 16; ++j) tile[Bw ^ j] = a[j];
    }
    __syncthreads();
    // R4: l = (tid&31) | (j<<5) | ((tid>>5)<<9): gates y14..17 (m5..8)
    {
        const int b4 = (tid & 31) | ((tid >> 5) << 9);
#pragma unroll
        for (int j = 0; j < 16; ++j) a[j] = tile[b4 + (j << 5)];
        gateN<0,16>(a, G2 + 4 * 14); gateN<1,16>(a, G2 + 4 * 15);
        gateN<2,16>(a, G2 + 4 * 16); gateN<3,16>(a, G2 + 4 * 17);
        __syncthreads();
#pragma unroll
        for (int j = 0; j < 16; ++j) tile[b4 + (j << 5)] = a[j];
    }
    __syncthreads();
    // R5: l = tid | (j<<9): gates y18..21 (m9..12 = reg bits 0..3) + global store.
    //     y addr: y0..3 = m0..3 ; y4..12 = W ^ (m4 ? 0x1FF : 0) ; y13..21 = m4..12
    {
#pragma unroll
        for (int j = 0; j < 16; ++j) a[j] = tile[tid + (j << 9)];
        gateN<0,16>(a, G2 + 4 * 18); gateN<1,16>(a, G2 + 4 * 19);
        gateN<2,16>(a, G2 + 4 * 20); gateN<3,16>(a, G2 + 4 * 21);
        const int Y9 = W ^ (((tid >> 4) & 1) ? 0x1FF : 0);
        cplx* gB = bufB + ((tid & 15) | (Y9 << 4) | (((tid >> 4) & 31) << 13));
#pragma unroll
        for (int j = 0; j < 16; ++j) gB[j << 18] = a[j];
    }
}

// ------------- kC: G2 gates y4..y13 + probs ---------------------------------
// 1024 thr, 16384-amp tile (128KiB dynamic LDS), tile bits l0..13 = y0..13,
// wg = y14..21 (256 blocks = 1/CU). bufB/out addresses = l | (wg<<14).
__global__ __launch_bounds__(1024, 4) void kC(const cplx* __restrict__ tab,
                                              const cplx* __restrict__ bufB, float* __restrict__ out) {
    extern __shared__ cplx tileC[];
    const int wg = blockIdx.x;
    const int tid = threadIdx.x;  // 10 bits
    const cplx* G2 = tab + T_G2;
    const int base = wg << 14;
    cplx a[16];
    // R0: load (128B runs); l = (tid&15) | (j<<4) | ((tid>>4)<<8): gates y4..7
    {
        const cplx* gB = bufB + base + ((tid & 15) | ((tid >> 4) << 8));
#pragma unroll
        for (int j = 0; j < 16; ++j) a[j] = gB[j << 4];
        gateN<0,16>(a, G2 + 4 * 4); gateN<1,16>(a, G2 + 4 * 5);
        gateN<2,16>(a, G2 + 4 * 6); gateN<3,16>(a, G2 + 4 * 7);
        const int b0 = (tid & 15) | ((tid >> 4) << 8);
#pragma unroll
        for (int j = 0; j < 16; ++j) tileC[b0 + (j << 4)] = a[j];
    }
    __syncthreads();
    // R1: l = (tid&255) | (j<<8) | ((tid>>8)<<12): gates y8..11
    {
        const int b1 = (tid & 255) | ((tid >> 8) << 12);
#pragma unroll
        for (int j = 0; j < 16; ++j) a[j] = tileC[b1 + (j << 8)];
        gateN<0,16>(a, G2 + 4 * 8);  gateN<1,16>(a, G2 + 4 * 9);
        gateN<2,16>(a, G2 + 4 * 10); gateN<3,16>(a, G2 + 4 * 11);
        __syncthreads();
#pragma unroll
        for (int j = 0; j < 16; ++j) tileC[b1 + (j << 8)] = a[j];
    }
    __syncthreads();
    // R2: l = tid | (j<<10): gates y12,y13 (reg bits 2,3) + probs + store (256B/wave)
    {
#pragma unroll
        for (int j = 0; j < 16; ++j) a[j] = tileC[tid + (j << 10)];
        gateN<2,16>(a, G2 + 4 * 12); gateN<3,16>(a, G2 + 4 * 13);
        float* gout = out + base + tid;
#pragma unroll
        for (int j = 0; j < 16; ++j)
            gout[j << 10] = fmaf(a[j].x, a[j].x, a[j].y * a[j].y);
    }
}

extern "C" void kernel_launch(void* const* d_in, const int* in_sizes, int n_in,
                              void* d_out, int out_size, void* d_ws, size_t ws_size,
                              hipStream_t stream) {
    const float* params = (const float*)d_in[0];   // (3, 66) float32
    cplx* bufA = (cplx*)d_ws;                      // 2^22 complex
    cplx* bufB = bufA + (1 << 22);                 // 2^22 complex
    cplx* tab  = bufA + (1 << 23);                 // ~704 float2 of tables
    float* out = (float*)d_out;                    // 2^22 float probs

    k_setup<<<1, 256, 0, stream>>>(params, tab);
    kA<<<512, 512, 0, stream>>>(tab, bufA);
    kB<<<512, 512, 0, stream>>>(tab, bufA, bufB);
    kC<<<256, 1024, 131072, stream>>>(tab, bufB, out);
}